// Round 3
// baseline (433.597 us; speedup 1.0000x reference)
//
#include <hip/hip_runtime.h>
#include <hip/hip_cooperative_groups.h>
#include <math.h>

namespace cg = cooperative_groups;

#define NODES 4096
#define FEATS 256
#define BATCH 1024
#define LR_C 0.5f
#define SIGMA_C 70.4f
#define GRID 512

typedef _Float16 f16x8 __attribute__((ext_vector_type(8)));
typedef float floatx4 __attribute__((ext_vector_type(4)));

__device__ __forceinline__ void get_params(int it, float& lr, float& r2, float& i2r2) {
    float decay = __expf(-(float)it * (SIGMA_C / 100000.0f));
    float radius = SIGMA_C * decay + 1e-6f;
    lr = LR_C * decay;
    r2 = radius * radius;
    i2r2 = 1.0f / (2.0f * r2);
}

// monotone float -> uint key (handles negatives); u64 key = (fkey << 32) | idx
__device__ __forceinline__ unsigned fkey(float f) {
    unsigned u = __float_as_uint(f);
    return (u & 0x80000000u) ? ~u : (u | 0x80000000u);
}
__device__ __forceinline__ float funkey(unsigned k) {
    unsigned u = (k & 0x80000000u) ? (k & 0x7fffffffu) : ~k;
    return __uint_as_float(u);
}
__device__ __forceinline__ unsigned long long shfl_xor_u64(unsigned long long v, int mask) {
    unsigned lo = (unsigned)v, hi = (unsigned)(v >> 32);
    lo = __shfl_xor(lo, mask, 64);
    hi = __shfl_xor(hi, mask, 64);
    return ((unsigned long long)hi << 32) | lo;
}

// Phases: 0 prep(W->fp16,w2, X->fp16+T, gmin init) | 1 gemm1+rowmin | 2 refine ->bmu
//         3 lrop+Svec | 4 gemm2 (ksplit2 -> P) | 5 combine -> out0
__global__ __launch_bounds__(256, 2) void mega(
    int ph0, int ph1, int coop,
    const float* __restrict__ X, const float* __restrict__ Wm, const int* __restrict__ itp,
    float* __restrict__ out0, float* __restrict__ out1,
    float* __restrict__ w2, _Float16* __restrict__ Xh, _Float16* __restrict__ XT,
    _Float16* __restrict__ Wh, int* __restrict__ bmu, float* __restrict__ Svec,
    _Float16* __restrict__ SdLr, float* __restrict__ P, unsigned long long* __restrict__ gmin)
{
    __shared__ _Float16 As[64][40];
    __shared__ _Float16 Bs[64][40];
    __shared__ _Float16 T[64][72];
    __shared__ unsigned long long rowmin[64][2];
    __shared__ int cand[128];
    __shared__ int cnt;
    __shared__ unsigned long long wbest[4];
    __shared__ int bmu_s[1024];
    __shared__ float texp[64];

    const int t = threadIdx.x;
    const int blk = blockIdx.x;
    const int wave = t >> 6, lane = t & 63;

    for (int ph = ph0; ph < ph1; ++ph) {
        if (ph == 0) {
            // ---- W -> fp16 + w2 (8 rows/block, wave per row)
#pragma unroll
            for (int rr = 0; rr < 2; ++rr) {
                int row = blk * 8 + wave * 2 + rr;
                float4 v = *(const float4*)&Wm[(size_t)row * FEATS + lane * 4];
                union { _Float16 h[4]; float2 f2; } u;
                u.h[0] = (_Float16)v.x; u.h[1] = (_Float16)v.y;
                u.h[2] = (_Float16)v.z; u.h[3] = (_Float16)v.w;
                *(float2*)&Wh[(size_t)row * FEATS + lane * 4] = u.f2;
                float s = v.x * v.x + v.y * v.y + v.z * v.z + v.w * v.w;
#pragma unroll
                for (int off = 32; off > 0; off >>= 1) s += __shfl_down(s, off, 64);
                if (lane == 0) w2[row] = s;
            }
            if (blk < 4) gmin[blk * 256 + t] = 0xFFFFFFFFFFFFFFFFULL;
            // ---- X -> fp16 (b-major) + fp16 transposed (blocks 0..63)
            if (blk < 64) {
                const int b0 = (blk & 15) * 64, d0 = (blk >> 4) * 64;
                {
                    const int bl = t >> 2, dq = (t & 3) * 16;
                    union { _Float16 h[16]; float4 q[2]; } u;
#pragma unroll
                    for (int c = 0; c < 4; ++c) {
                        float4 v = *(const float4*)&X[(size_t)(b0 + bl) * FEATS + d0 + dq + c * 4];
                        u.h[c * 4 + 0] = (_Float16)v.x; u.h[c * 4 + 1] = (_Float16)v.y;
                        u.h[c * 4 + 2] = (_Float16)v.z; u.h[c * 4 + 3] = (_Float16)v.w;
                    }
                    *(float4*)&Xh[(size_t)(b0 + bl) * FEATS + d0 + dq] = u.q[0];
                    *(float4*)&Xh[(size_t)(b0 + bl) * FEATS + d0 + dq + 8] = u.q[1];
#pragma unroll
                    for (int c = 0; c < 16; ++c) T[bl][dq + c] = u.h[c];
                }
                __syncthreads();
                {
                    const int dl = t >> 2, bq = (t & 3) * 16;
                    union { _Float16 h[16]; float4 q[2]; } u;
#pragma unroll
                    for (int c = 0; c < 16; ++c) u.h[c] = T[bq + c][dl];
                    *(float4*)&XT[(size_t)(d0 + dl) * BATCH + b0 + bq] = u.q[0];
                    *(float4*)&XT[(size_t)(d0 + dl) * BATCH + b0 + bq + 8] = u.q[1];
                }
            }
        } else if (ph == 1) {
            // ---- gemm1: sqd approx = w2 - 2*x@W^T (fp16 MFMA) + per-row packed min
            const int wm = wave & 1, wn = wave >> 1;
            const int lm = lane & 15, quad = lane >> 4;
            const int srow = t >> 2, skoff = (t & 3) * 8;
            for (int tile = blk; tile < 1024; tile += GRID) {
                const int n0 = (tile & 63) * 64;
                const int b0 = (tile >> 6) * 64;
                floatx4 acc[2][2] = {};
                for (int k0 = 0; k0 < FEATS; k0 += 32) {
                    *(float4*)&As[srow][skoff] = *(const float4*)&Xh[(size_t)(b0 + srow) * FEATS + k0 + skoff];
                    *(float4*)&Bs[srow][skoff] = *(const float4*)&Wh[(size_t)(n0 + srow) * FEATS + k0 + skoff];
                    __syncthreads();
                    f16x8 af0 = *(f16x8*)&As[wm * 32 + lm][quad * 8];
                    f16x8 af1 = *(f16x8*)&As[wm * 32 + 16 + lm][quad * 8];
                    f16x8 bf0 = *(f16x8*)&Bs[wn * 32 + lm][quad * 8];
                    f16x8 bf1 = *(f16x8*)&Bs[wn * 32 + 16 + lm][quad * 8];
                    acc[0][0] = __builtin_amdgcn_mfma_f32_16x16x32_f16(af0, bf0, acc[0][0], 0, 0, 0);
                    acc[0][1] = __builtin_amdgcn_mfma_f32_16x16x32_f16(af0, bf1, acc[0][1], 0, 0, 0);
                    acc[1][0] = __builtin_amdgcn_mfma_f32_16x16x32_f16(af1, bf0, acc[1][0], 0, 0, 0);
                    acc[1][1] = __builtin_amdgcn_mfma_f32_16x16x32_f16(af1, bf1, acc[1][1], 0, 0, 0);
                    __syncthreads();
                }
                const int col0 = n0 + wn * 32 + lm, col1 = col0 + 16;
                const float w20 = w2[col0], w21 = w2[col1];
#pragma unroll
                for (int i = 0; i < 2; ++i) {
#pragma unroll
                    for (int r = 0; r < 4; ++r) {
                        int row = b0 + wm * 32 + i * 16 + quad * 4 + r;
                        float va = w20 - 2.0f * acc[i][0][r];
                        float vb = w21 - 2.0f * acc[i][1][r];
                        SdLr[(size_t)row * NODES + col0] = (_Float16)va;
                        SdLr[(size_t)row * NODES + col1] = (_Float16)vb;
                        unsigned long long ka = ((unsigned long long)fkey(va) << 32) | (unsigned)col0;
                        unsigned long long kb = ((unsigned long long)fkey(vb) << 32) | (unsigned)col1;
                        unsigned long long m = ka < kb ? ka : kb;
#pragma unroll
                        for (int mk = 1; mk < 16; mk <<= 1) {
                            unsigned long long o = shfl_xor_u64(m, mk);
                            if (o < m) m = o;
                        }
                        if (lm == 0) rowmin[wm * 32 + i * 16 + quad * 4 + r][wn] = m;
                    }
                }
                __syncthreads();
                if (t < 64) {
                    unsigned long long v = rowmin[t][0];
                    if (rowmin[t][1] < v) v = rowmin[t][1];
                    atomicMin(&gmin[b0 + t], v);
                }
                __syncthreads();
            }
        } else if (ph == 2) {
            // ---- refine: margin scan + exact fp32 dot over candidates
            for (int b = blk; b < BATCH; b += GRID) {
                if (t == 0) cnt = 0;
                if (t < 4) wbest[t] = 0xFFFFFFFFFFFFFFFFULL;
                __syncthreads();
                const _Float16* row = SdLr + (size_t)b * NODES;
                const float thr = funkey((unsigned)(gmin[b] >> 32)) + 0.4f;
#pragma unroll
                for (int j = 0; j < 2; ++j) {
                    f16x8 h = *(const f16x8*)&row[j * 2048 + t * 8];
#pragma unroll
                    for (int u = 0; u < 8; ++u) {
                        if ((float)h[u] <= thr) {
                            int p = atomicAdd(&cnt, 1);
                            if (p < 128) cand[p] = j * 2048 + t * 8 + u;
                        }
                    }
                }
                __syncthreads();
                const int C = cnt < 128 ? cnt : 128;
                float4 xv = *(const float4*)&X[(size_t)b * FEATS + lane * 4];
                unsigned long long best = 0xFFFFFFFFFFFFFFFFULL;
                for (int c = wave; c < C; c += 4) {
                    int n = cand[c];
                    float4 wv = *(const float4*)&Wm[(size_t)n * FEATS + lane * 4];
                    float d = xv.x * wv.x + xv.y * wv.y + xv.z * wv.z + xv.w * wv.w;
#pragma unroll
                    for (int off = 32; off > 0; off >>= 1) d += __shfl_down(d, off, 64);
                    if (lane == 0) {
                        float ex = w2[n] - 2.0f * d;
                        unsigned long long k = ((unsigned long long)fkey(ex) << 32) | (unsigned)n;
                        if (k < best) best = k;
                    }
                }
                if (lane == 0) wbest[wave] = best;
                __syncthreads();
                if (t == 0) {
                    unsigned long long bb = wbest[0];
#pragma unroll
                    for (int w2i = 1; w2i < 4; ++w2i) if (wbest[w2i] < bb) bb = wbest[w2i];
                    int idx = (int)(bb & 0xFFFFFFFFULL);
                    bmu[b] = idx;
                    out1[b] = (float)idx;
                }
                __syncthreads();
            }
        } else if (ph == 3) {
            // ---- lr_op^T fp16 (NODES x BATCH, aliases Sd) + Svec
#pragma unroll
            for (int j = 0; j < 4; ++j) bmu_s[t + j * 256] = bmu[t + j * 256];
            float lr, r2, i2r2;
            get_params(itp[0], lr, r2, i2r2);
            if (t < 64) texp[t] = __expf(-(float)(t * t) * i2r2);
            __syncthreads();
            const int n = blk * 8 + (t >> 5);
            const int b0 = (t & 31) * 32;
            const int ni = n >> 6, nj = n & 63;
            float s = 0.0f;
            union { _Float16 h[32]; float4 q[4]; } u;
#pragma unroll
            for (int c = 0; c < 32; ++c) {
                int m = bmu_s[b0 + c];
                int di = ni - (m >> 6); di = di < 0 ? -di : di;
                int dj = nj - (m & 63); dj = dj < 0 ? -dj : dj;
                int d2 = di * di + dj * dj;
                float val = ((float)d2 <= r2) ? lr * texp[di] * texp[dj] : 0.0f;
                u.h[c] = (_Float16)val;
                s += val;
            }
#pragma unroll
            for (int q4 = 0; q4 < 4; ++q4)
                *(float4*)&SdLr[(size_t)n * BATCH + b0 + q4 * 8] = u.q[q4];
#pragma unroll
            for (int off = 16; off > 0; off >>= 1) s += __shfl_down(s, off, 32);
            if ((t & 31) == 0) Svec[n] = s;
        } else if (ph == 4) {
            // ---- gemm2: P[z] = lr_op^T @ x (fp16 MFMA), one unit per block
            const int z = blk >> 8, rest = blk & 255;
            const int d0 = (rest & 3) * 64, n0 = (rest >> 2) * 64;
            const int wm = wave & 1, wn = wave >> 1;
            const int lm = lane & 15, quad = lane >> 4;
            const int srow = t >> 2, skoff = (t & 3) * 8;
            const size_t kbase = (size_t)z * 512;
            floatx4 acc[2][2] = {};
            for (int k0 = 0; k0 < 512; k0 += 32) {
                *(float4*)&As[srow][skoff] = *(const float4*)&SdLr[(size_t)(n0 + srow) * BATCH + kbase + k0 + skoff];
                *(float4*)&Bs[srow][skoff] = *(const float4*)&XT[(size_t)(d0 + srow) * BATCH + kbase + k0 + skoff];
                __syncthreads();
                f16x8 af0 = *(f16x8*)&As[wm * 32 + lm][quad * 8];
                f16x8 af1 = *(f16x8*)&As[wm * 32 + 16 + lm][quad * 8];
                f16x8 bf0 = *(f16x8*)&Bs[wn * 32 + lm][quad * 8];
                f16x8 bf1 = *(f16x8*)&Bs[wn * 32 + 16 + lm][quad * 8];
                acc[0][0] = __builtin_amdgcn_mfma_f32_16x16x32_f16(af0, bf0, acc[0][0], 0, 0, 0);
                acc[0][1] = __builtin_amdgcn_mfma_f32_16x16x32_f16(af0, bf1, acc[0][1], 0, 0, 0);
                acc[1][0] = __builtin_amdgcn_mfma_f32_16x16x32_f16(af1, bf0, acc[1][0], 0, 0, 0);
                acc[1][1] = __builtin_amdgcn_mfma_f32_16x16x32_f16(af1, bf1, acc[1][1], 0, 0, 0);
                __syncthreads();
            }
            float* Pz = P + (size_t)z * NODES * FEATS;
#pragma unroll
            for (int i = 0; i < 2; ++i)
#pragma unroll
                for (int j = 0; j < 2; ++j) {
                    int col = d0 + wn * 32 + j * 16 + lm;
#pragma unroll
                    for (int r = 0; r < 4; ++r) {
                        int row = n0 + wm * 32 + i * 16 + quad * 4 + r;
                        Pz[(size_t)row * FEATS + col] = acc[i][j][r];
                    }
                }
        } else {
            // ---- combine: out0 = w*(1 - S/B) + (P0+P1)/B
            const float invB = 1.0f / (float)BATCH;
#pragma unroll
            for (int it2 = 0; it2 < 2; ++it2) {
                int g = it2 * (GRID * 256) + blk * 256 + t;
                int n = g >> 6;
                float4 w4 = *(const float4*)&Wm[(size_t)g * 4];
                float4 p0 = *(const float4*)&P[(size_t)g * 4];
                float4 p1 = *(const float4*)&P[(size_t)NODES * FEATS + (size_t)g * 4];
                float c = 1.0f - Svec[n] * invB;
                float4 o;
                o.x = w4.x * c + (p0.x + p1.x) * invB;
                o.y = w4.y * c + (p0.y + p1.y) * invB;
                o.z = w4.z * c + (p0.z + p1.z) * invB;
                o.w = w4.w * c + (p0.w + p1.w) * invB;
                *(float4*)&out0[(size_t)g * 4] = o;
            }
        }
        if (coop && ph + 1 < ph1) cg::this_grid().sync();
    }
}

extern "C" void kernel_launch(void* const* d_in, const int* in_sizes, int n_in,
                              void* d_out, int out_size, void* d_ws, size_t ws_size,
                              hipStream_t stream) {
    const float* X = (const float*)d_in[0];    // (1024, 256)
    const float* Wm = (const float*)d_in[1];   // (4096, 256)
    const int* itp = (const int*)d_in[2];      // scalar iteration
    float* out0 = (float*)d_out;
    float* out1 = out0 + (size_t)NODES * FEATS;

    char* ws = (char*)d_ws;
    float* w2       = (float*)(ws + 0);              // 16 KB
    _Float16* Xh    = (_Float16*)(ws + 16384);       // 512 KB
    _Float16* XT    = (_Float16*)(ws + 540672);      // 512 KB
    _Float16* Wh    = (_Float16*)(ws + 1064960);     // 2 MB
    int* bmu        = (int*)(ws + 3162112);          // 4 KB
    float* Svec     = (float*)(ws + 3166208);        // 16 KB
    _Float16* SdLr  = (_Float16*)(ws + 3182592);     // 8 MB (Sd fp16, reused as lrT)
    float* P        = (float*)(ws + 11571200);       // 8 MB (2 fp32 partials)
    unsigned long long* gmin = (unsigned long long*)(ws + 19959808);  // 8 KB

    int ph0 = 0, ph1 = 6, coop = 1;
    void* args[] = { &ph0, &ph1, &coop, &X, &Wm, &itp, &out0, &out1,
                     &w2, &Xh, &XT, &Wh, &bmu, &Svec, &SdLr, &P, &gmin };
    hipError_t e = hipLaunchCooperativeKernel((const void*)mega, dim3(GRID), dim3(256), args, 0, stream);
    if (e != hipSuccess) {
        (void)hipGetLastError();
        for (int p = 0; p < 6; ++p)
            mega<<<GRID, 256, 0, stream>>>(p, p + 1, 0, X, Wm, itp, out0, out1,
                                           w2, Xh, XT, Wh, bmu, Svec, SdLr, P, gmin);
    }
}

// Round 4
// 123.024 us; speedup vs baseline: 3.5245x; 3.5245x over previous
//
#include <hip/hip_runtime.h>
#include <math.h>

#define NODES 4096
#define FEATS 256
#define BATCH 1024
#define LR_C 0.5f
#define SIGMA_C 70.4f

typedef _Float16 f16x8 __attribute__((ext_vector_type(8)));
typedef float floatx4 __attribute__((ext_vector_type(4)));

__device__ __forceinline__ void get_params(int it, float& lr, float& r2, float& i2r2) {
    float decay = __expf(-(float)it * (SIGMA_C / 100000.0f));
    float radius = SIGMA_C * decay + 1e-6f;
    lr = LR_C * decay;
    r2 = radius * radius;
    i2r2 = 1.0f / (2.0f * r2);
}

// monotone float -> uint key; u64 key = (fkey << 32) | idx (ties -> smaller idx)
__device__ __forceinline__ unsigned fkey(float f) {
    unsigned u = __float_as_uint(f);
    return (u & 0x80000000u) ? ~u : (u | 0x80000000u);
}
__device__ __forceinline__ float funkey(unsigned k) {
    unsigned u = (k & 0x80000000u) ? (k & 0x7fffffffu) : ~k;
    return __uint_as_float(u);
}
__device__ __forceinline__ unsigned long long shfl_xor_u64(unsigned long long v, int mask) {
    unsigned lo = (unsigned)v, hi = (unsigned)(v >> 32);
    lo = __shfl_xor(lo, mask, 64);
    hi = __shfl_xor(hi, mask, 64);
    return ((unsigned long long)hi << 32) | lo;
}

// ---- K1: W->fp16 + w2 (all 512 blocks); X->fp16 b-major + d-major (blocks 0..63);
//          gmin init (blocks 0..3).
__global__ __launch_bounds__(256) void k_prep(const float* __restrict__ Wm, const float* __restrict__ X,
                                              _Float16* __restrict__ Wh, float* __restrict__ w2,
                                              _Float16* __restrict__ Xh, _Float16* __restrict__ XT,
                                              unsigned long long* __restrict__ gmin) {
    __shared__ _Float16 T[64][72];
    const int t = threadIdx.x;
    const int blk = blockIdx.x;
    const int wave = t >> 6, lane = t & 63;
#pragma unroll
    for (int rr = 0; rr < 2; ++rr) {
        int row = blk * 8 + wave * 2 + rr;
        float4 v = *(const float4*)&Wm[(size_t)row * FEATS + lane * 4];
        union { _Float16 h[4]; float2 f2; } u;
        u.h[0] = (_Float16)v.x; u.h[1] = (_Float16)v.y;
        u.h[2] = (_Float16)v.z; u.h[3] = (_Float16)v.w;
        *(float2*)&Wh[(size_t)row * FEATS + lane * 4] = u.f2;
        float s = v.x * v.x + v.y * v.y + v.z * v.z + v.w * v.w;
#pragma unroll
        for (int off = 32; off > 0; off >>= 1) s += __shfl_down(s, off, 64);
        if (lane == 0) w2[row] = s;
    }
    if (blk < 4) gmin[blk * 256 + t] = 0xFFFFFFFFFFFFFFFFULL;
    if (blk < 64) {
        const int b0 = (blk & 15) * 64, d0 = (blk >> 4) * 64;
        {
            const int bl = t >> 2, dq = (t & 3) * 16;
            union { _Float16 h[16]; float4 q[2]; } u;
#pragma unroll
            for (int c = 0; c < 4; ++c) {
                float4 v = *(const float4*)&X[(size_t)(b0 + bl) * FEATS + d0 + dq + c * 4];
                u.h[c * 4 + 0] = (_Float16)v.x; u.h[c * 4 + 1] = (_Float16)v.y;
                u.h[c * 4 + 2] = (_Float16)v.z; u.h[c * 4 + 3] = (_Float16)v.w;
            }
            *(float4*)&Xh[(size_t)(b0 + bl) * FEATS + d0 + dq] = u.q[0];
            *(float4*)&Xh[(size_t)(b0 + bl) * FEATS + d0 + dq + 8] = u.q[1];
#pragma unroll
            for (int c = 0; c < 16; ++c) T[bl][dq + c] = u.h[c];
        }
        __syncthreads();
        {
            const int dl = t >> 2, bq = (t & 3) * 16;
            union { _Float16 h[16]; float4 q[2]; } u;
#pragma unroll
            for (int c = 0; c < 16; ++c) u.h[c] = T[bq + c][dl];
            *(float4*)&XT[(size_t)(d0 + dl) * BATCH + b0 + bq] = u.q[0];
            *(float4*)&XT[(size_t)(d0 + dl) * BATCH + b0 + bq + 8] = u.q[1];
        }
    }
}

// ---- K2: sqd approx = w2 - 2*x@W^T (fp16 MFMA) -> Sd fp16, + per-row packed atomicMin.
__global__ __launch_bounds__(256) void k_gemm1min(const _Float16* __restrict__ Xh, const _Float16* __restrict__ Wh,
                                                  const float* __restrict__ w2, _Float16* __restrict__ Sd,
                                                  unsigned long long* __restrict__ gmin) {
    __shared__ _Float16 As[64][40];
    __shared__ _Float16 Bs[64][40];
    __shared__ unsigned long long rowmin[64][2];
    const int n0 = blockIdx.x * 64;
    const int b0 = blockIdx.y * 64;
    const int t = threadIdx.x;
    const int wave = t >> 6, lane = t & 63;
    const int wm = wave & 1, wn = wave >> 1;
    const int lm = lane & 15, quad = lane >> 4;
    const int srow = t >> 2, skoff = (t & 3) * 8;
    floatx4 acc[2][2] = {};
    for (int k0 = 0; k0 < FEATS; k0 += 32) {
        *(float4*)&As[srow][skoff] = *(const float4*)&Xh[(size_t)(b0 + srow) * FEATS + k0 + skoff];
        *(float4*)&Bs[srow][skoff] = *(const float4*)&Wh[(size_t)(n0 + srow) * FEATS + k0 + skoff];
        __syncthreads();
        f16x8 af0 = *(f16x8*)&As[wm * 32 + lm][quad * 8];
        f16x8 af1 = *(f16x8*)&As[wm * 32 + 16 + lm][quad * 8];
        f16x8 bf0 = *(f16x8*)&Bs[wn * 32 + lm][quad * 8];
        f16x8 bf1 = *(f16x8*)&Bs[wn * 32 + 16 + lm][quad * 8];
        acc[0][0] = __builtin_amdgcn_mfma_f32_16x16x32_f16(af0, bf0, acc[0][0], 0, 0, 0);
        acc[0][1] = __builtin_amdgcn_mfma_f32_16x16x32_f16(af0, bf1, acc[0][1], 0, 0, 0);
        acc[1][0] = __builtin_amdgcn_mfma_f32_16x16x32_f16(af1, bf0, acc[1][0], 0, 0, 0);
        acc[1][1] = __builtin_amdgcn_mfma_f32_16x16x32_f16(af1, bf1, acc[1][1], 0, 0, 0);
        __syncthreads();
    }
    const int col0 = n0 + wn * 32 + lm, col1 = col0 + 16;
    const float w20 = w2[col0], w21 = w2[col1];
#pragma unroll
    for (int i = 0; i < 2; ++i) {
#pragma unroll
        for (int r = 0; r < 4; ++r) {
            int row = b0 + wm * 32 + i * 16 + quad * 4 + r;
            float va = w20 - 2.0f * acc[i][0][r];
            float vb = w21 - 2.0f * acc[i][1][r];
            Sd[(size_t)row * NODES + col0] = (_Float16)va;
            Sd[(size_t)row * NODES + col1] = (_Float16)vb;
            unsigned long long ka = ((unsigned long long)fkey(va) << 32) | (unsigned)col0;
            unsigned long long kb = ((unsigned long long)fkey(vb) << 32) | (unsigned)col1;
            unsigned long long m = ka < kb ? ka : kb;
#pragma unroll
            for (int mk = 1; mk < 16; mk <<= 1) {
                unsigned long long o = shfl_xor_u64(m, mk);
                if (o < m) m = o;
            }
            if (lm == 0) rowmin[wm * 32 + i * 16 + quad * 4 + r][wn] = m;
        }
    }
    __syncthreads();
    if (t < 64) {
        unsigned long long v = rowmin[t][0];
        if (rowmin[t][1] < v) v = rowmin[t][1];
        atomicMin(&gmin[b0 + t], v);
    }
}

// ---- K3: per-sample margin scan + exact fp32 refine -> bmu, out1.
__global__ __launch_bounds__(256) void k_refine(const _Float16* __restrict__ Sd, const float* __restrict__ X,
                                                const float* __restrict__ Wm, const float* __restrict__ w2,
                                                const unsigned long long* __restrict__ gmin,
                                                int* __restrict__ bmu, float* __restrict__ out1) {
    __shared__ int cand[128];
    __shared__ int cnt;
    __shared__ unsigned long long wbest[4];
    const int b = blockIdx.x;
    const int t = threadIdx.x;
    const int wave = t >> 6, lane = t & 63;
    if (t == 0) cnt = 0;
    if (t < 4) wbest[t] = 0xFFFFFFFFFFFFFFFFULL;
    __syncthreads();
    const _Float16* row = Sd + (size_t)b * NODES;
    const float thr = funkey((unsigned)(gmin[b] >> 32)) + 0.4f;  // margin >> fp16 error
#pragma unroll
    for (int j = 0; j < 2; ++j) {
        f16x8 h = *(const f16x8*)&row[j * 2048 + t * 8];
#pragma unroll
        for (int u = 0; u < 8; ++u) {
            if ((float)h[u] <= thr) {
                int p = atomicAdd(&cnt, 1);
                if (p < 128) cand[p] = j * 2048 + t * 8 + u;
            }
        }
    }
    __syncthreads();
    const int C = cnt < 128 ? cnt : 128;
    float4 xv = *(const float4*)&X[(size_t)b * FEATS + lane * 4];
    unsigned long long best = 0xFFFFFFFFFFFFFFFFULL;
    for (int c = wave; c < C; c += 4) {
        int n = cand[c];
        float4 wv = *(const float4*)&Wm[(size_t)n * FEATS + lane * 4];
        float d = xv.x * wv.x + xv.y * wv.y + xv.z * wv.z + xv.w * wv.w;
#pragma unroll
        for (int off = 32; off > 0; off >>= 1) d += __shfl_down(d, off, 64);
        if (lane == 0) {
            float ex = w2[n] - 2.0f * d;
            unsigned long long k = ((unsigned long long)fkey(ex) << 32) | (unsigned)n;
            if (k < best) best = k;
        }
    }
    if (lane == 0) wbest[wave] = best;
    __syncthreads();
    if (t == 0) {
        unsigned long long bb = wbest[0];
#pragma unroll
        for (int w = 1; w < 4; ++w) if (wbest[w] < bb) bb = wbest[w];
        int idx = (int)(bb & 0xFFFFFFFFULL);
        bmu[b] = idx;
        out1[b] = (float)idx;
    }
}

// ---- K4: fused gemm2: A = lr_op^T synthesized in-register (exp table), full K=1024,
//          local Svec via shuffles, combine epilogue -> out0.
__global__ __launch_bounds__(256) void k_gemm2f(const _Float16* __restrict__ XT, const int* __restrict__ bmu,
                                                const int* __restrict__ itp, const float* __restrict__ Wm,
                                                float* __restrict__ out0) {
    __shared__ _Float16 As[64][40];
    __shared__ _Float16 Bs[64][40];
    __shared__ int bmu_s[1024];
    __shared__ float texp[64];
    __shared__ float Svl[64];
    const int d0 = blockIdx.x * 64;
    const int n0 = blockIdx.y * 64;
    const int t = threadIdx.x;
    const int wave = t >> 6, lane = t & 63;
    const int wm = wave & 1, wn = wave >> 1;
    const int lm = lane & 15, quad = lane >> 4;
#pragma unroll
    for (int j = 0; j < 4; ++j) bmu_s[t + j * 256] = bmu[t + j * 256];
    float lr, r2, i2r2;
    get_params(itp[0], lr, r2, i2r2);
    if (t < 64) texp[t] = __expf(-(float)(t * t) * i2r2);
    __syncthreads();
    const int nl = t >> 2, kq = (t & 3) * 8;
    const int ni = (n0 + nl) >> 6, nj = (n0 + nl) & 63;
    float s = 0.0f;
    floatx4 acc[2][2] = {};
    for (int c = 0; c < 32; ++c) {
        const int kb = c * 32;
        union { _Float16 h[8]; float4 q; } u;
#pragma unroll
        for (int e = 0; e < 8; ++e) {
            int m = bmu_s[kb + kq + e];
            int di = ni - (m >> 6); di = di < 0 ? -di : di;
            int dj = nj - (m & 63); dj = dj < 0 ? -dj : dj;
            int d2 = di * di + dj * dj;
            float val = ((float)d2 <= r2) ? lr * texp[di] * texp[dj] : 0.0f;
            u.h[e] = (_Float16)val;
            s += val;
        }
        *(float4*)&As[nl][kq] = u.q;
        *(float4*)&Bs[nl][kq] = *(const float4*)&XT[(size_t)(d0 + nl) * BATCH + kb + kq];
        __syncthreads();
        f16x8 af0 = *(f16x8*)&As[wm * 32 + lm][quad * 8];
        f16x8 af1 = *(f16x8*)&As[wm * 32 + 16 + lm][quad * 8];
        f16x8 bf0 = *(f16x8*)&Bs[wn * 32 + lm][quad * 8];
        f16x8 bf1 = *(f16x8*)&Bs[wn * 32 + 16 + lm][quad * 8];
        acc[0][0] = __builtin_amdgcn_mfma_f32_16x16x32_f16(af0, bf0, acc[0][0], 0, 0, 0);
        acc[0][1] = __builtin_amdgcn_mfma_f32_16x16x32_f16(af0, bf1, acc[0][1], 0, 0, 0);
        acc[1][0] = __builtin_amdgcn_mfma_f32_16x16x32_f16(af1, bf0, acc[1][0], 0, 0, 0);
        acc[1][1] = __builtin_amdgcn_mfma_f32_16x16x32_f16(af1, bf1, acc[1][1], 0, 0, 0);
        __syncthreads();
    }
    // Svec for node nl: sum across the 4 consecutive lanes covering its k-range
    s += __shfl_xor(s, 1, 64);
    s += __shfl_xor(s, 2, 64);
    if ((t & 3) == 0) Svl[nl] = s;
    __syncthreads();
    const float invB = 1.0f / (float)BATCH;
#pragma unroll
    for (int i = 0; i < 2; ++i)
#pragma unroll
        for (int j = 0; j < 2; ++j) {
            int col = d0 + wn * 32 + j * 16 + lm;
#pragma unroll
            for (int r = 0; r < 4; ++r) {
                int rowN = n0 + wm * 32 + i * 16 + quad * 4 + r;
                float cc = 1.0f - Svl[rowN - n0] * invB;
                out0[(size_t)rowN * FEATS + col] =
                    Wm[(size_t)rowN * FEATS + col] * cc + acc[i][j][r] * invB;
            }
        }
}

extern "C" void kernel_launch(void* const* d_in, const int* in_sizes, int n_in,
                              void* d_out, int out_size, void* d_ws, size_t ws_size,
                              hipStream_t stream) {
    const float* X = (const float*)d_in[0];    // (1024, 256)
    const float* Wm = (const float*)d_in[1];   // (4096, 256)
    const int* itp = (const int*)d_in[2];      // scalar iteration
    float* out0 = (float*)d_out;
    float* out1 = out0 + (size_t)NODES * FEATS;

    char* ws = (char*)d_ws;
    float* w2       = (float*)(ws + 0);              // 16 KB
    _Float16* Xh    = (_Float16*)(ws + 16384);       // 512 KB
    _Float16* XT    = (_Float16*)(ws + 540672);      // 512 KB
    _Float16* Wh    = (_Float16*)(ws + 1064960);     // 2 MB
    int* bmu        = (int*)(ws + 3162112);          // 4 KB
    unsigned long long* gmin = (unsigned long long*)(ws + 3166208);  // 8 KB
    _Float16* Sd    = (_Float16*)(ws + 3182592);     // 8 MB

    k_prep<<<512, 256, 0, stream>>>(Wm, X, Wh, w2, Xh, XT, gmin);
    k_gemm1min<<<dim3(64, 16), 256, 0, stream>>>(Xh, Wh, w2, Sd, gmin);
    k_refine<<<1024, 256, 0, stream>>>(Sd, X, Wm, w2, gmin, bmu, out1);
    k_gemm2f<<<dim3(4, 64), 256, 0, stream>>>(XT, bmu, itp, Wm, out0);
}

// Round 5
// 108.318 us; speedup vs baseline: 4.0030x; 1.1358x over previous
//
#include <hip/hip_runtime.h>
#include <math.h>

#define NODES 4096
#define FEATS 256
#define BATCH 1024
#define LR_C 0.5f
#define SIGMA_C 70.4f

typedef _Float16 f16x8 __attribute__((ext_vector_type(8)));
typedef float floatx4 __attribute__((ext_vector_type(4)));

__device__ __forceinline__ void get_params(int it, float& lr, float& r2, float& i2r2) {
    float decay = __expf(-(float)it * (SIGMA_C / 100000.0f));
    float radius = SIGMA_C * decay + 1e-6f;
    lr = LR_C * decay;
    r2 = radius * radius;
    i2r2 = 1.0f / (2.0f * r2);
}

// monotone float -> uint key; u64 key = (fkey << 32) | idx (ties -> smaller idx)
__device__ __forceinline__ unsigned fkey(float f) {
    unsigned u = __float_as_uint(f);
    return (u & 0x80000000u) ? ~u : (u | 0x80000000u);
}
__device__ __forceinline__ float funkey(unsigned k) {
    unsigned u = (k & 0x80000000u) ? (k & 0x7fffffffu) : ~k;
    return __uint_as_float(u);
}
__device__ __forceinline__ unsigned long long shfl_xor_u64(unsigned long long v, int mask) {
    unsigned lo = (unsigned)v, hi = (unsigned)(v >> 32);
    lo = __shfl_xor(lo, mask, 64);
    hi = __shfl_xor(hi, mask, 64);
    return ((unsigned long long)hi << 32) | lo;
}

// ---- K1: W->fp16 + w2 (all 512 blocks); X->fp16 b-major + d-major (blocks 0..63);
//          gmin init (blocks 0..3).
__global__ __launch_bounds__(256) void k_prep(const float* __restrict__ Wm, const float* __restrict__ X,
                                              _Float16* __restrict__ Wh, float* __restrict__ w2,
                                              _Float16* __restrict__ Xh, _Float16* __restrict__ XT,
                                              unsigned long long* __restrict__ gmin) {
    __shared__ _Float16 T[64][72];
    const int t = threadIdx.x;
    const int blk = blockIdx.x;
    const int wave = t >> 6, lane = t & 63;
#pragma unroll
    for (int rr = 0; rr < 2; ++rr) {
        int row = blk * 8 + wave * 2 + rr;
        float4 v = *(const float4*)&Wm[(size_t)row * FEATS + lane * 4];
        union { _Float16 h[4]; float2 f2; } u;
        u.h[0] = (_Float16)v.x; u.h[1] = (_Float16)v.y;
        u.h[2] = (_Float16)v.z; u.h[3] = (_Float16)v.w;
        *(float2*)&Wh[(size_t)row * FEATS + lane * 4] = u.f2;
        float s = v.x * v.x + v.y * v.y + v.z * v.z + v.w * v.w;
#pragma unroll
        for (int off = 32; off > 0; off >>= 1) s += __shfl_down(s, off, 64);
        if (lane == 0) w2[row] = s;
    }
    if (blk < 4) gmin[blk * 256 + t] = 0xFFFFFFFFFFFFFFFFULL;
    if (blk < 64) {
        const int b0 = (blk & 15) * 64, d0 = (blk >> 4) * 64;
        {
            const int bl = t >> 2, dq = (t & 3) * 16;
            union { _Float16 h[16]; float4 q[2]; } u;
#pragma unroll
            for (int c = 0; c < 4; ++c) {
                float4 v = *(const float4*)&X[(size_t)(b0 + bl) * FEATS + d0 + dq + c * 4];
                u.h[c * 4 + 0] = (_Float16)v.x; u.h[c * 4 + 1] = (_Float16)v.y;
                u.h[c * 4 + 2] = (_Float16)v.z; u.h[c * 4 + 3] = (_Float16)v.w;
            }
            *(float4*)&Xh[(size_t)(b0 + bl) * FEATS + d0 + dq] = u.q[0];
            *(float4*)&Xh[(size_t)(b0 + bl) * FEATS + d0 + dq + 8] = u.q[1];
#pragma unroll
            for (int c = 0; c < 16; ++c) T[bl][dq + c] = u.h[c];
        }
        __syncthreads();
        {
            const int dl = t >> 2, bq = (t & 3) * 16;
            union { _Float16 h[16]; float4 q[2]; } u;
#pragma unroll
            for (int c = 0; c < 16; ++c) u.h[c] = T[bq + c][dl];
            *(float4*)&XT[(size_t)(d0 + dl) * BATCH + b0 + bq] = u.q[0];
            *(float4*)&XT[(size_t)(d0 + dl) * BATCH + b0 + bq + 8] = u.q[1];
        }
    }
}

// ---- K2: sqd approx = w2 - 2*x@W^T (fp16 MFMA) -> Sd fp16, + per-row packed atomicMin.
__global__ __launch_bounds__(256) void k_gemm1min(const _Float16* __restrict__ Xh, const _Float16* __restrict__ Wh,
                                                  const float* __restrict__ w2, _Float16* __restrict__ Sd,
                                                  unsigned long long* __restrict__ gmin) {
    __shared__ _Float16 As[64][40];
    __shared__ _Float16 Bs[64][40];
    __shared__ unsigned long long rowmin[64][2];
    const int n0 = blockIdx.x * 64;
    const int b0 = blockIdx.y * 64;
    const int t = threadIdx.x;
    const int wave = t >> 6, lane = t & 63;
    const int wm = wave & 1, wn = wave >> 1;
    const int lm = lane & 15, quad = lane >> 4;
    const int srow = t >> 2, skoff = (t & 3) * 8;
    floatx4 acc[2][2] = {};
    for (int k0 = 0; k0 < FEATS; k0 += 32) {
        *(float4*)&As[srow][skoff] = *(const float4*)&Xh[(size_t)(b0 + srow) * FEATS + k0 + skoff];
        *(float4*)&Bs[srow][skoff] = *(const float4*)&Wh[(size_t)(n0 + srow) * FEATS + k0 + skoff];
        __syncthreads();
        f16x8 af0 = *(f16x8*)&As[wm * 32 + lm][quad * 8];
        f16x8 af1 = *(f16x8*)&As[wm * 32 + 16 + lm][quad * 8];
        f16x8 bf0 = *(f16x8*)&Bs[wn * 32 + lm][quad * 8];
        f16x8 bf1 = *(f16x8*)&Bs[wn * 32 + 16 + lm][quad * 8];
        acc[0][0] = __builtin_amdgcn_mfma_f32_16x16x32_f16(af0, bf0, acc[0][0], 0, 0, 0);
        acc[0][1] = __builtin_amdgcn_mfma_f32_16x16x32_f16(af0, bf1, acc[0][1], 0, 0, 0);
        acc[1][0] = __builtin_amdgcn_mfma_f32_16x16x32_f16(af1, bf0, acc[1][0], 0, 0, 0);
        acc[1][1] = __builtin_amdgcn_mfma_f32_16x16x32_f16(af1, bf1, acc[1][1], 0, 0, 0);
        __syncthreads();
    }
    const int col0 = n0 + wn * 32 + lm, col1 = col0 + 16;
    const float w20 = w2[col0], w21 = w2[col1];
#pragma unroll
    for (int i = 0; i < 2; ++i) {
#pragma unroll
        for (int r = 0; r < 4; ++r) {
            int row = b0 + wm * 32 + i * 16 + quad * 4 + r;
            float va = w20 - 2.0f * acc[i][0][r];
            float vb = w21 - 2.0f * acc[i][1][r];
            Sd[(size_t)row * NODES + col0] = (_Float16)va;
            Sd[(size_t)row * NODES + col1] = (_Float16)vb;
            unsigned long long ka = ((unsigned long long)fkey(va) << 32) | (unsigned)col0;
            unsigned long long kb = ((unsigned long long)fkey(vb) << 32) | (unsigned)col1;
            unsigned long long m = ka < kb ? ka : kb;
#pragma unroll
            for (int mk = 1; mk < 16; mk <<= 1) {
                unsigned long long o = shfl_xor_u64(m, mk);
                if (o < m) m = o;
            }
            if (lm == 0) rowmin[wm * 32 + i * 16 + quad * 4 + r][wn] = m;
        }
    }
    __syncthreads();
    if (t < 64) {
        unsigned long long v = rowmin[t][0];
        if (rowmin[t][1] < v) v = rowmin[t][1];
        atomicMin(&gmin[b0 + t], v);
    }
}

// ---- K3: per-sample margin scan + exact fp32 refine -> bmu, out1.
__global__ __launch_bounds__(256) void k_refine(const _Float16* __restrict__ Sd, const float* __restrict__ X,
                                                const float* __restrict__ Wm, const float* __restrict__ w2,
                                                const unsigned long long* __restrict__ gmin,
                                                int* __restrict__ bmu, float* __restrict__ out1) {
    __shared__ int cand[128];
    __shared__ int cnt;
    __shared__ unsigned long long wbest[4];
    const int b = blockIdx.x;
    const int t = threadIdx.x;
    const int wave = t >> 6, lane = t & 63;
    if (t == 0) cnt = 0;
    if (t < 4) wbest[t] = 0xFFFFFFFFFFFFFFFFULL;
    __syncthreads();
    const _Float16* row = Sd + (size_t)b * NODES;
    const float thr = funkey((unsigned)(gmin[b] >> 32)) + 0.4f;  // margin >> fp16 error
#pragma unroll
    for (int j = 0; j < 2; ++j) {
        f16x8 h = *(const f16x8*)&row[j * 2048 + t * 8];
#pragma unroll
        for (int u = 0; u < 8; ++u) {
            if ((float)h[u] <= thr) {
                int p = atomicAdd(&cnt, 1);
                if (p < 128) cand[p] = j * 2048 + t * 8 + u;
            }
        }
    }
    __syncthreads();
    const int C = cnt < 128 ? cnt : 128;
    float4 xv = *(const float4*)&X[(size_t)b * FEATS + lane * 4];
    unsigned long long best = 0xFFFFFFFFFFFFFFFFULL;
    for (int c = wave; c < C; c += 4) {
        int n = cand[c];
        float4 wv = *(const float4*)&Wm[(size_t)n * FEATS + lane * 4];
        float d = xv.x * wv.x + xv.y * wv.y + xv.z * wv.z + xv.w * wv.w;
#pragma unroll
        for (int off = 32; off > 0; off >>= 1) d += __shfl_down(d, off, 64);
        if (lane == 0) {
            float ex = w2[n] - 2.0f * d;
            unsigned long long k = ((unsigned long long)fkey(ex) << 32) | (unsigned)n;
            if (k < best) best = k;
        }
    }
    if (lane == 0) wbest[wave] = best;
    __syncthreads();
    if (t == 0) {
        unsigned long long bb = wbest[0];
#pragma unroll
        for (int w = 1; w < 4; ++w) if (wbest[w] < bb) bb = wbest[w];
        int idx = (int)(bb & 0xFFFFFFFFULL);
        bmu[b] = idx;
        out1[b] = (float)idx;
    }
}

// ---- K4: lr_op^T fp16 (NODES x BATCH) + Svec[n]. exp via LDS table. 2 nodes/block.
__global__ __launch_bounds__(256) void k_lrop(const int* __restrict__ bmu, const int* __restrict__ itp,
                                              _Float16* __restrict__ lrT, float* __restrict__ Svec) {
    __shared__ int bmu_s[1024];
    __shared__ float texp[64];
    __shared__ float red4[4];
    const int t = threadIdx.x;
#pragma unroll
    for (int j = 0; j < 4; ++j) bmu_s[t + j * 256] = bmu[t + j * 256];
    float lr, r2, i2r2;
    get_params(itp[0], lr, r2, i2r2);
    if (t < 64) texp[t] = __expf(-(float)(t * t) * i2r2);
    __syncthreads();
    const int n = blockIdx.x * 2 + (t >> 7);
    const int b0 = (t & 127) * 8;
    const int ni = n >> 6, nj = n & 63;
    float s = 0.0f;
    union { _Float16 h[8]; float4 q; } u;
#pragma unroll
    for (int c = 0; c < 8; ++c) {
        int m = bmu_s[b0 + c];
        int di = ni - (m >> 6); di = di < 0 ? -di : di;
        int dj = nj - (m & 63); dj = dj < 0 ? -dj : dj;
        int d2 = di * di + dj * dj;
        float val = ((float)d2 <= r2) ? lr * texp[di] * texp[dj] : 0.0f;
        u.h[c] = (_Float16)val;
        s += val;
    }
    *(float4*)&lrT[(size_t)n * BATCH + b0] = u.q;
    const int lane = t & 63, wave = t >> 6;
#pragma unroll
    for (int off = 32; off > 0; off >>= 1) s += __shfl_down(s, off, 64);
    if (lane == 0) red4[wave] = s;
    __syncthreads();
    if (t < 2) Svec[blockIdx.x * 2 + t] = red4[2 * t] + red4[2 * t + 1];
}

// ---- K5: pure fp16-MFMA GEMM (lr_op^T @ x), 32n x 64d tiles, full K=1024,
//          fused combine epilogue: out0 = Wm*(1 - Svec/B) + acc/B.
__global__ __launch_bounds__(256) void k_gemm2c(const _Float16* __restrict__ lrT, const _Float16* __restrict__ XT,
                                                const float* __restrict__ Svec, const float* __restrict__ Wm,
                                                float* __restrict__ out0) {
    __shared__ _Float16 As[32][40];
    __shared__ _Float16 Bs[64][40];
    __shared__ float Svl[32];
    const int d0 = blockIdx.x * 64;
    const int n0 = blockIdx.y * 32;
    const int t = threadIdx.x;
    const int wave = t >> 6, lane = t & 63;
    const int wm = wave & 1, wn = wave >> 1;
    const int lm = lane & 15, quad = lane >> 4;
    const int srow = t >> 2, skoff = (t & 3) * 8;
    if (t < 32) Svl[t] = Svec[n0 + t];
    floatx4 acc0 = {}, acc1 = {};
    for (int k0 = 0; k0 < BATCH; k0 += 32) {
        if (t < 128)
            *(float4*)&As[srow][skoff] = *(const float4*)&lrT[(size_t)(n0 + srow) * BATCH + k0 + skoff];
        *(float4*)&Bs[srow][skoff] = *(const float4*)&XT[(size_t)(d0 + srow) * BATCH + k0 + skoff];
        __syncthreads();
        f16x8 af = *(f16x8*)&As[wm * 16 + lm][quad * 8];
        f16x8 bf0 = *(f16x8*)&Bs[wn * 32 + lm][quad * 8];
        f16x8 bf1 = *(f16x8*)&Bs[wn * 32 + 16 + lm][quad * 8];
        acc0 = __builtin_amdgcn_mfma_f32_16x16x32_f16(af, bf0, acc0, 0, 0, 0);
        acc1 = __builtin_amdgcn_mfma_f32_16x16x32_f16(af, bf1, acc1, 0, 0, 0);
        __syncthreads();
    }
    const float invB = 1.0f / (float)BATCH;
#pragma unroll
    for (int r = 0; r < 4; ++r) {
        int rowN = n0 + wm * 16 + quad * 4 + r;
        float cc = 1.0f - Svl[rowN - n0] * invB;
        int col0 = d0 + wn * 32 + lm;
        int col1 = col0 + 16;
        out0[(size_t)rowN * FEATS + col0] = Wm[(size_t)rowN * FEATS + col0] * cc + acc0[r] * invB;
        out0[(size_t)rowN * FEATS + col1] = Wm[(size_t)rowN * FEATS + col1] * cc + acc1[r] * invB;
    }
}

extern "C" void kernel_launch(void* const* d_in, const int* in_sizes, int n_in,
                              void* d_out, int out_size, void* d_ws, size_t ws_size,
                              hipStream_t stream) {
    const float* X = (const float*)d_in[0];    // (1024, 256)
    const float* Wm = (const float*)d_in[1];   // (4096, 256)
    const int* itp = (const int*)d_in[2];      // scalar iteration
    float* out0 = (float*)d_out;
    float* out1 = out0 + (size_t)NODES * FEATS;

    char* ws = (char*)d_ws;
    float* w2       = (float*)(ws + 0);              // 16 KB
    _Float16* Xh    = (_Float16*)(ws + 16384);       // 512 KB
    _Float16* XT    = (_Float16*)(ws + 540672);      // 512 KB
    _Float16* Wh    = (_Float16*)(ws + 1064960);     // 2 MB
    int* bmu        = (int*)(ws + 3162112);          // 4 KB
    unsigned long long* gmin = (unsigned long long*)(ws + 3166208);  // 8 KB
    float* Svec     = (float*)(ws + 3174400);        // 16 KB
    _Float16* Sd    = (_Float16*)(ws + 3190784);     // 8 MB (approx sqd; reused as lrT)
    _Float16* lrT   = (_Float16*)(ws + 3190784);     // aliases Sd (dead after refine)

    k_prep<<<512, 256, 0, stream>>>(Wm, X, Wh, w2, Xh, XT, gmin);
    k_gemm1min<<<dim3(64, 16), 256, 0, stream>>>(Xh, Wh, w2, Sd, gmin);
    k_refine<<<1024, 256, 0, stream>>>(Sd, X, Wm, w2, gmin, bmu, out1);
    k_lrop<<<2048, 256, 0, stream>>>(bmu, itp, lrT, Svec);
    k_gemm2c<<<dim3(4, 128), 256, 0, stream>>>(lrT, XT, Svec, Wm, out0);
}

// Round 6
// 95.414 us; speedup vs baseline: 4.5444x; 1.1352x over previous
//
#include <hip/hip_runtime.h>
#include <math.h>

#define NODES 4096
#define FEATS 256
#define BATCH 1024
#define LR_C 0.5f
#define SIGMA_C 70.4f

typedef _Float16 f16x8 __attribute__((ext_vector_type(8)));
typedef float floatx4 __attribute__((ext_vector_type(4)));

__device__ __forceinline__ void get_params(int it, float& lr, float& r2, float& i2r2) {
    float decay = __expf(-(float)it * (SIGMA_C / 100000.0f));
    float radius = SIGMA_C * decay + 1e-6f;
    lr = LR_C * decay;
    r2 = radius * radius;
    i2r2 = 1.0f / (2.0f * r2);
}

// monotone float -> uint key; u64 key = (fkey << 32) | idx (ties -> smaller idx)
__device__ __forceinline__ unsigned fkey(float f) {
    unsigned u = __float_as_uint(f);
    return (u & 0x80000000u) ? ~u : (u | 0x80000000u);
}
__device__ __forceinline__ unsigned long long shfl_xor_u64(unsigned long long v, int mask) {
    unsigned lo = (unsigned)v, hi = (unsigned)(v >> 32);
    lo = __shfl_xor(lo, mask, 64);
    hi = __shfl_xor(hi, mask, 64);
    return ((unsigned long long)hi << 32) | lo;
}

// ---- K1: W -> fp16 hi/lo + w2 (all 512 blocks); X -> fp16 hi/lo b-major + hi d-major
//          (blocks 0..63); gmin init (blocks 0..3).
__global__ __launch_bounds__(256) void k_prep(const float* __restrict__ Wm, const float* __restrict__ X,
                                              _Float16* __restrict__ Whi, _Float16* __restrict__ Wlo,
                                              float* __restrict__ w2,
                                              _Float16* __restrict__ Xhi, _Float16* __restrict__ Xlo,
                                              _Float16* __restrict__ XT,
                                              unsigned long long* __restrict__ gmin) {
    __shared__ _Float16 T[64][72];
    const int t = threadIdx.x;
    const int blk = blockIdx.x;
    const int wave = t >> 6, lane = t & 63;
#pragma unroll
    for (int rr = 0; rr < 2; ++rr) {
        int row = blk * 8 + wave * 2 + rr;
        float4 v = *(const float4*)&Wm[(size_t)row * FEATS + lane * 4];
        union { _Float16 h[4]; float2 f2; } uh, ul;
        uh.h[0] = (_Float16)v.x; uh.h[1] = (_Float16)v.y;
        uh.h[2] = (_Float16)v.z; uh.h[3] = (_Float16)v.w;
        ul.h[0] = (_Float16)(v.x - (float)uh.h[0]);
        ul.h[1] = (_Float16)(v.y - (float)uh.h[1]);
        ul.h[2] = (_Float16)(v.z - (float)uh.h[2]);
        ul.h[3] = (_Float16)(v.w - (float)uh.h[3]);
        *(float2*)&Whi[(size_t)row * FEATS + lane * 4] = uh.f2;
        *(float2*)&Wlo[(size_t)row * FEATS + lane * 4] = ul.f2;
        float s = v.x * v.x + v.y * v.y + v.z * v.z + v.w * v.w;
#pragma unroll
        for (int off = 32; off > 0; off >>= 1) s += __shfl_down(s, off, 64);
        if (lane == 0) w2[row] = s;
    }
    if (blk < 4) gmin[blk * 256 + t] = 0xFFFFFFFFFFFFFFFFULL;
    if (blk < 64) {
        const int b0 = (blk & 15) * 64, d0 = (blk >> 4) * 64;
        {
            const int bl = t >> 2, dq = (t & 3) * 16;
            union { _Float16 h[16]; float4 q[2]; } uh, ul;
#pragma unroll
            for (int c = 0; c < 4; ++c) {
                float4 v = *(const float4*)&X[(size_t)(b0 + bl) * FEATS + d0 + dq + c * 4];
                uh.h[c * 4 + 0] = (_Float16)v.x; uh.h[c * 4 + 1] = (_Float16)v.y;
                uh.h[c * 4 + 2] = (_Float16)v.z; uh.h[c * 4 + 3] = (_Float16)v.w;
                ul.h[c * 4 + 0] = (_Float16)(v.x - (float)uh.h[c * 4 + 0]);
                ul.h[c * 4 + 1] = (_Float16)(v.y - (float)uh.h[c * 4 + 1]);
                ul.h[c * 4 + 2] = (_Float16)(v.z - (float)uh.h[c * 4 + 2]);
                ul.h[c * 4 + 3] = (_Float16)(v.w - (float)uh.h[c * 4 + 3]);
            }
            *(float4*)&Xhi[(size_t)(b0 + bl) * FEATS + d0 + dq] = uh.q[0];
            *(float4*)&Xhi[(size_t)(b0 + bl) * FEATS + d0 + dq + 8] = uh.q[1];
            *(float4*)&Xlo[(size_t)(b0 + bl) * FEATS + d0 + dq] = ul.q[0];
            *(float4*)&Xlo[(size_t)(b0 + bl) * FEATS + d0 + dq + 8] = ul.q[1];
#pragma unroll
            for (int c = 0; c < 16; ++c) T[bl][dq + c] = uh.h[c];
        }
        __syncthreads();
        {
            const int dl = t >> 2, bq = (t & 3) * 16;
            union { _Float16 h[16]; float4 q[2]; } u;
#pragma unroll
            for (int c = 0; c < 16; ++c) u.h[c] = T[bq + c][dl];
            *(float4*)&XT[(size_t)(d0 + dl) * BATCH + b0 + bq] = u.q[0];
            *(float4*)&XT[(size_t)(d0 + dl) * BATCH + b0 + bq + 8] = u.q[1];
        }
    }
}

// ---- K2: fp32-accurate sqd via fp16-split MFMA (xh*wh + xh*wl + xl*wh),
//          per-row packed-u64 atomicMin -> gmin. No Sd materialization.
__global__ __launch_bounds__(256) void k_gemm1min(const _Float16* __restrict__ Xhi, const _Float16* __restrict__ Xlo,
                                                  const _Float16* __restrict__ Whi, const _Float16* __restrict__ Wlo,
                                                  const float* __restrict__ w2,
                                                  unsigned long long* __restrict__ gmin) {
    __shared__ _Float16 Ah[64][40];
    __shared__ _Float16 Al[64][40];
    __shared__ _Float16 Bh[64][40];
    __shared__ _Float16 Bl[64][40];
    __shared__ unsigned long long rowmin[64][2];
    const int n0 = blockIdx.x * 64;
    const int b0 = blockIdx.y * 64;
    const int t = threadIdx.x;
    const int wave = t >> 6, lane = t & 63;
    const int wm = wave & 1, wn = wave >> 1;
    const int lm = lane & 15, quad = lane >> 4;
    const int srow = t >> 2, skoff = (t & 3) * 8;
    floatx4 acc[2][2] = {};
    for (int k0 = 0; k0 < FEATS; k0 += 32) {
        *(float4*)&Ah[srow][skoff] = *(const float4*)&Xhi[(size_t)(b0 + srow) * FEATS + k0 + skoff];
        *(float4*)&Al[srow][skoff] = *(const float4*)&Xlo[(size_t)(b0 + srow) * FEATS + k0 + skoff];
        *(float4*)&Bh[srow][skoff] = *(const float4*)&Whi[(size_t)(n0 + srow) * FEATS + k0 + skoff];
        *(float4*)&Bl[srow][skoff] = *(const float4*)&Wlo[(size_t)(n0 + srow) * FEATS + k0 + skoff];
        __syncthreads();
        f16x8 ah[2], al[2], bh[2], bl[2];
        ah[0] = *(f16x8*)&Ah[wm * 32 + lm][quad * 8];
        ah[1] = *(f16x8*)&Ah[wm * 32 + 16 + lm][quad * 8];
        al[0] = *(f16x8*)&Al[wm * 32 + lm][quad * 8];
        al[1] = *(f16x8*)&Al[wm * 32 + 16 + lm][quad * 8];
        bh[0] = *(f16x8*)&Bh[wn * 32 + lm][quad * 8];
        bh[1] = *(f16x8*)&Bh[wn * 32 + 16 + lm][quad * 8];
        bl[0] = *(f16x8*)&Bl[wn * 32 + lm][quad * 8];
        bl[1] = *(f16x8*)&Bl[wn * 32 + 16 + lm][quad * 8];
#pragma unroll
        for (int i = 0; i < 2; ++i)
#pragma unroll
            for (int j = 0; j < 2; ++j) {
                acc[i][j] = __builtin_amdgcn_mfma_f32_16x16x32_f16(ah[i], bh[j], acc[i][j], 0, 0, 0);
                acc[i][j] = __builtin_amdgcn_mfma_f32_16x16x32_f16(ah[i], bl[j], acc[i][j], 0, 0, 0);
                acc[i][j] = __builtin_amdgcn_mfma_f32_16x16x32_f16(al[i], bh[j], acc[i][j], 0, 0, 0);
            }
        __syncthreads();
    }
    const int col0 = n0 + wn * 32 + lm, col1 = col0 + 16;
    const float w20 = w2[col0], w21 = w2[col1];
#pragma unroll
    for (int i = 0; i < 2; ++i) {
#pragma unroll
        for (int r = 0; r < 4; ++r) {
            float va = w20 - 2.0f * acc[i][0][r];
            float vb = w21 - 2.0f * acc[i][1][r];
            unsigned long long ka = ((unsigned long long)fkey(va) << 32) | (unsigned)col0;
            unsigned long long kb = ((unsigned long long)fkey(vb) << 32) | (unsigned)col1;
            unsigned long long m = ka < kb ? ka : kb;
#pragma unroll
            for (int mk = 1; mk < 16; mk <<= 1) {
                unsigned long long o = shfl_xor_u64(m, mk);
                if (o < m) m = o;
            }
            if (lm == 0) rowmin[wm * 32 + i * 16 + quad * 4 + r][wn] = m;
        }
    }
    __syncthreads();
    if (t < 64) {
        unsigned long long v = rowmin[t][0];
        if (rowmin[t][1] < v) v = rowmin[t][1];
        atomicMin(&gmin[b0 + t], v);
    }
}

// ---- K3: bmu extraction from gmin (+out1 in blocks 0..3), lr_op^T fp16 + Svec.
__global__ __launch_bounds__(256) void k_lropB(const unsigned long long* __restrict__ gmin,
                                               const int* __restrict__ itp,
                                               _Float16* __restrict__ lrT, float* __restrict__ Svec,
                                               float* __restrict__ out1) {
    __shared__ int bmu_s[1024];
    __shared__ float texp[64];
    __shared__ float red4[4];
    const int t = threadIdx.x;
    const int blk = blockIdx.x;
#pragma unroll
    for (int j = 0; j < 4; ++j)
        bmu_s[t + j * 256] = (int)(gmin[t + j * 256] & 0xFFFFFFFFULL);
    float lr, r2, i2r2;
    get_params(itp[0], lr, r2, i2r2);
    if (t < 64) texp[t] = __expf(-(float)(t * t) * i2r2);
    __syncthreads();
    if (blk < 4) out1[blk * 256 + t] = (float)bmu_s[blk * 256 + t];
    const int n = blk * 2 + (t >> 7);
    const int b0 = (t & 127) * 8;
    const int ni = n >> 6, nj = n & 63;
    float s = 0.0f;
    union { _Float16 h[8]; float4 q; } u;
#pragma unroll
    for (int c = 0; c < 8; ++c) {
        int m = bmu_s[b0 + c];
        int di = ni - (m >> 6); di = di < 0 ? -di : di;
        int dj = nj - (m & 63); dj = dj < 0 ? -dj : dj;
        int d2 = di * di + dj * dj;
        float val = ((float)d2 <= r2) ? lr * texp[di] * texp[dj] : 0.0f;
        u.h[c] = (_Float16)val;
        s += val;
    }
    *(float4*)&lrT[(size_t)n * BATCH + b0] = u.q;
    const int lane = t & 63, wave = t >> 6;
#pragma unroll
    for (int off = 32; off > 0; off >>= 1) s += __shfl_down(s, off, 64);
    if (lane == 0) red4[wave] = s;
    __syncthreads();
    if (t < 2) Svec[blk * 2 + t] = red4[2 * t] + red4[2 * t + 1];
}

// ---- K4: fp16-MFMA GEMM (lr_op^T @ x), 32n x 64d tile, BK=128 (8 MFMA/barrier),
//          fused combine epilogue: out0 = Wm*(1 - Svec/B) + acc/B.
__global__ __launch_bounds__(256) void k_gemm2c(const _Float16* __restrict__ lrT, const _Float16* __restrict__ XT,
                                                const float* __restrict__ Svec, const float* __restrict__ Wm,
                                                float* __restrict__ out0) {
    __shared__ _Float16 As[32][136];
    __shared__ _Float16 Bs[64][136];
    __shared__ float Svl[32];
    const int d0 = blockIdx.x * 64;
    const int n0 = blockIdx.y * 32;
    const int t = threadIdx.x;
    const int wave = t >> 6, lane = t & 63;
    const int wm = wave & 1, wn = wave >> 1;
    const int lm = lane & 15, quad = lane >> 4;
    if (t < 32) Svl[t] = Svec[n0 + t];
    const int arow = t >> 3, acoff = (t & 7) * 16;
    const int brow = t >> 2, bcoff = (t & 3) * 32;
    floatx4 acc0 = {}, acc1 = {};
    for (int k0 = 0; k0 < BATCH; k0 += 128) {
        *(float4*)&As[arow][acoff] = *(const float4*)&lrT[(size_t)(n0 + arow) * BATCH + k0 + acoff];
        *(float4*)&As[arow][acoff + 8] = *(const float4*)&lrT[(size_t)(n0 + arow) * BATCH + k0 + acoff + 8];
#pragma unroll
        for (int c = 0; c < 4; ++c)
            *(float4*)&Bs[brow][bcoff + c * 8] =
                *(const float4*)&XT[(size_t)(d0 + brow) * BATCH + k0 + bcoff + c * 8];
        __syncthreads();
#pragma unroll
        for (int ks = 0; ks < 128; ks += 32) {
            f16x8 a = *(f16x8*)&As[wm * 16 + lm][ks + quad * 8];
            f16x8 b0 = *(f16x8*)&Bs[wn * 32 + lm][ks + quad * 8];
            f16x8 b1 = *(f16x8*)&Bs[wn * 32 + 16 + lm][ks + quad * 8];
            acc0 = __builtin_amdgcn_mfma_f32_16x16x32_f16(a, b0, acc0, 0, 0, 0);
            acc1 = __builtin_amdgcn_mfma_f32_16x16x32_f16(a, b1, acc1, 0, 0, 0);
        }
        __syncthreads();
    }
    const float invB = 1.0f / (float)BATCH;
#pragma unroll
    for (int r = 0; r < 4; ++r) {
        int rowN = n0 + wm * 16 + quad * 4 + r;
        float cc = 1.0f - Svl[rowN - n0] * invB;
        int col0 = d0 + wn * 32 + lm;
        int col1 = col0 + 16;
        out0[(size_t)rowN * FEATS + col0] = Wm[(size_t)rowN * FEATS + col0] * cc + acc0[r] * invB;
        out0[(size_t)rowN * FEATS + col1] = Wm[(size_t)rowN * FEATS + col1] * cc + acc1[r] * invB;
    }
}

extern "C" void kernel_launch(void* const* d_in, const int* in_sizes, int n_in,
                              void* d_out, int out_size, void* d_ws, size_t ws_size,
                              hipStream_t stream) {
    const float* X = (const float*)d_in[0];    // (1024, 256)
    const float* Wm = (const float*)d_in[1];   // (4096, 256)
    const int* itp = (const int*)d_in[2];      // scalar iteration
    float* out0 = (float*)d_out;
    float* out1 = out0 + (size_t)NODES * FEATS;

    char* ws = (char*)d_ws;
    float* w2       = (float*)(ws + 0);              // 16 KB
    _Float16* Xhi   = (_Float16*)(ws + 16384);       // 512 KB
    _Float16* Xlo   = (_Float16*)(ws + 540672);      // 512 KB
    _Float16* XT    = (_Float16*)(ws + 1064960);     // 512 KB
    _Float16* Whi   = (_Float16*)(ws + 1589248);     // 2 MB
    _Float16* Wlo   = (_Float16*)(ws + 3686400);     // 2 MB
    unsigned long long* gmin = (unsigned long long*)(ws + 5783552);  // 8 KB
    float* Svec     = (float*)(ws + 5791744);        // 16 KB
    _Float16* lrT   = (_Float16*)(ws + 5808128);     // 8 MB

    k_prep<<<512, 256, 0, stream>>>(Wm, X, Whi, Wlo, w2, Xhi, Xlo, XT, gmin);
    k_gemm1min<<<dim3(64, 16), 256, 0, stream>>>(Xhi, Xlo, Whi, Wlo, w2, gmin);
    k_lropB<<<2048, 256, 0, stream>>>(gmin, itp, lrT, Svec, out1);
    k_gemm2c<<<dim3(4, 128), 256, 0, stream>>>(lrT, XT, Svec, Wm, out0);
}